// Round 5
// baseline (271.583 us; speedup 1.0000x reference)
//
#include <hip/hip_runtime.h>
#include <hip/hip_bf16.h>

#define BATCH 8
#define SEQ 4096
#define EMB 1024
#define HEAD 64
#define N3 192      // 3*HEAD: k | q | v
#define KQ_STR 128  // dense K|Q row stride

typedef __attribute__((ext_vector_type(4))) float f32x4;
typedef __attribute__((ext_vector_type(8))) short bf16x8;
typedef __attribute__((ext_vector_type(4))) float float4v;
typedef __attribute__((ext_vector_type(4))) unsigned int u32x4;

#define LOG2E 1.4426950408889634f

static __device__ __forceinline__ unsigned short f2bf(float f) {
  unsigned int x = __builtin_bit_cast(unsigned int, f);
  x += 0x7fffu + ((x >> 16) & 1u);   // RTNE
  return (unsigned short)(x >> 16);
}

// --- Kernel 1: W [1024][192] f32 -> Wt [192][1024] bf16 ---
__global__ __launch_bounds__(256) void wt_kernel(const float* __restrict__ W,
                                                 unsigned short* __restrict__ Wt) {
  int idx = blockIdx.x * 256 + threadIdx.x;
  int k = idx / N3, c = idx % N3;
  Wt[(size_t)c * EMB + k] = f2bf(W[idx]);
}

// --- Kernel 2: kq[32768][128] = [K|Q] bf16 (Q pre-scaled 0.125), Vt[B][64][4096] bf16 ---
// 1024 blocks x 512 threads. Block owns 32 rows; wave w: row-group (w>>2)*16,
// col-group (w&3) -> 3 MFMA tiles (48 cols). 8192 waves = 100% occupancy.
__global__ __launch_bounds__(512, 8) void qkv_kernel(const float* __restrict__ x,
                                                     const unsigned short* __restrict__ Wt,
                                                     unsigned short* __restrict__ kq,
                                                     unsigned short* __restrict__ Vt) {
  const int wid = threadIdx.x >> 6;
  const int lane = threadIdx.x & 63;
  const int l16 = lane & 15;
  const int lg = lane >> 4;
  const int rowg = wid >> 2;
  const int colg = wid & 3;          // tiles t = 3*colg + {0,1,2}
  const int m0 = blockIdx.x * 32 + rowg * 16;

  f32x4 acc[3];
#pragma unroll
  for (int j = 0; j < 3; ++j) acc[j] = (f32x4)0.0f;

  const float* xrow = x + (size_t)(m0 + l16) * EMB;
  const unsigned short* wt0 = Wt + (size_t)((3 * colg + 0) * 16 + l16) * EMB + lg * 8;
  const unsigned short* wt1 = Wt + (size_t)((3 * colg + 1) * 16 + l16) * EMB + lg * 8;
  const unsigned short* wt2 = Wt + (size_t)((3 * colg + 2) * 16 + l16) * EMB + lg * 8;

  for (int kc = 0; kc < EMB; kc += 32) {
    float4v a0 = *(const float4v*)(xrow + kc + lg * 8);
    float4v a1 = *(const float4v*)(xrow + kc + lg * 8 + 4);
    bf16x8 af;
#pragma unroll
    for (int j = 0; j < 4; ++j) {
      af[j] = (short)f2bf(a0[j]);
      af[4 + j] = (short)f2bf(a1[j]);
    }
    bf16x8 b0 = *(const bf16x8*)(wt0 + kc);
    bf16x8 b1 = *(const bf16x8*)(wt1 + kc);
    bf16x8 b2 = *(const bf16x8*)(wt2 + kc);
    acc[0] = __builtin_amdgcn_mfma_f32_16x16x32_bf16(af, b0, acc[0], 0, 0, 0);
    acc[1] = __builtin_amdgcn_mfma_f32_16x16x32_bf16(af, b1, acc[1], 0, 0, 0);
    acc[2] = __builtin_amdgcn_mfma_f32_16x16x32_bf16(af, b2, acc[2], 0, 0, 0);
  }

  // D layout: col = t*16+l16, row = m0 + lg*4 + r
#pragma unroll
  for (int j = 0; j < 3; ++j) {
    const int t = 3 * colg + j;
#pragma unroll
    for (int r = 0; r < 4; ++r) {
      int row = m0 + lg * 4 + r;
      float v = acc[j][r];
      if (t >= 4 && t < 8) v *= 0.125f;   // q pre-scale 1/sqrt(64)
      unsigned short h = f2bf(v);
      if (t < 8) {
        kq[(size_t)row * KQ_STR + t * 16 + l16] = h;
      } else {
        int bb = row >> 12;
        int ss = row & (SEQ - 1);
        Vt[((size_t)bb * HEAD + (t - 8) * 16 + l16) * SEQ + ss] = h;
      }
    }
  }
}

// --- Kernel 3: causal flash attention, barrier-free, one 16-row q-chunk per wave ---
__global__ __launch_bounds__(256) void attn_kernel(const unsigned short* __restrict__ kq,
                                                   const unsigned short* __restrict__ Vt,
                                                   float* __restrict__ out) {
  const int tid = threadIdx.x;
  const int wid = tid >> 6;
  const int lane = tid & 63;
  const int l16 = lane & 15;
  const int lg = lane >> 4;

  // block B and B+256 carry complementary chunk lengths; batch = blockIdx%8 (XCD affinity)
  const int Bid = blockIdx.x;
  const int half = Bid >> 8;
  const int rr = Bid & 255;
  const int b = rr & 7;
  const int ii = rr >> 3;          // [0,32)
  int qc = 4 * ii + wid;           // [0,128)
  if (half) qc = 255 - qc;         // [128,256)
  const int q0 = qc * 16;
  const int ntiles = (q0 + 16 + 63) >> 6;

  const unsigned short* kqb = kq + (size_t)b * SEQ * KQ_STR;
  const unsigned short* vtb = Vt + (size_t)b * HEAD * SEQ;

  // Q fragments (B-operand of S^T mfma): col=l16 -> q row, k=lg*8+j -> d
  bf16x8 qf0 = *(const bf16x8*)(kqb + (size_t)(q0 + l16) * KQ_STR + 64 + lg * 8);
  bf16x8 qf1 = *(const bf16x8*)(kqb + (size_t)(q0 + l16) * KQ_STR + 96 + lg * 8);

  f32x4 o[4];
#pragma unroll
  for (int dd = 0; dd < 4; ++dd) o[dd] = (f32x4)0.0f;
  float m_ = -3.0e38f, lsum = 0.0f;

  // preload K tile 0 (A-operand: row=l16 -> kv, k=lg*8+j -> d)
  bf16x8 kf[8], kn[8];
#pragma unroll
  for (int t = 0; t < 4; ++t) {
    const unsigned short* kp = kqb + (size_t)(t * 16 + l16) * KQ_STR + lg * 8;
    kf[2 * t] = *(const bf16x8*)(kp);
    kf[2 * t + 1] = *(const bf16x8*)(kp + 32);
  }

  for (int it = 0; it < ntiles; ++it) {
    const int kv0 = it << 6;

    // prefetch next K tile (clamped; covered by this tile's compute)
    int kvn = kv0 + 64;
    if (kvn > SEQ - 64) kvn = SEQ - 64;
#pragma unroll
    for (int t = 0; t < 4; ++t) {
      const unsigned short* kp = kqb + (size_t)(kvn + t * 16 + l16) * KQ_STR + lg * 8;
      kn[2 * t] = *(const bf16x8*)(kp);
      kn[2 * t + 1] = *(const bf16x8*)(kp + 32);
    }
    // V fragments for this tile (A-operand of PV: row=l16 -> d, k -> kv)
    bf16x8 vf[8];
#pragma unroll
    for (int dd = 0; dd < 4; ++dd) {
      const unsigned short* vp = vtb + (size_t)(dd * 16 + l16) * SEQ + kv0 + lg * 8;
      vf[2 * dd] = *(const bf16x8*)(vp);
      vf[2 * dd + 1] = *(const bf16x8*)(vp + 32);
    }

    // S^T[kv][q]: lane holds kv = kv0+16t+lg*4+r for q = q0+l16
    f32x4 s[4];
#pragma unroll
    for (int t = 0; t < 4; ++t) {
      f32x4 z = (f32x4)0.0f;
      z = __builtin_amdgcn_mfma_f32_16x16x32_bf16(kf[2 * t], qf0, z, 0, 0, 0);
      z = __builtin_amdgcn_mfma_f32_16x16x32_bf16(kf[2 * t + 1], qf1, z, 0, 0, 0);
      s[t] = z;
    }

    // causal mask only on diagonal-crossing tiles (uniform branch)
    if (kv0 + 64 > q0) {
      const int base = kv0 + lg * 4 - q0 - l16;   // masked iff base + 16t + r > 0
#pragma unroll
      for (int t = 0; t < 4; ++t)
#pragma unroll
        for (int r = 0; r < 4; ++r)
          if (base + 16 * t + r > 0) s[t][r] = -3.0e38f;
    }

    // row max: 15 in-lane fmax + 2 shfl (across lg groups)
    float mx = s[0][0];
#pragma unroll
    for (int t = 0; t < 4; ++t)
#pragma unroll
      for (int r = 0; r < 4; ++r)
        mx = fmaxf(mx, s[t][r]);
    mx = fmaxf(mx, __shfl_xor(mx, 16));
    mx = fmaxf(mx, __shfl_xor(mx, 32));

    // defer-max: rescale only when some row's max grew
    if (!__all(mx <= m_)) {
      float mn = fmaxf(m_, mx);
      float al = exp2f((m_ - mn) * LOG2E);
      m_ = mn;
      lsum *= al;
#pragma unroll
      for (int dd = 0; dd < 4; ++dd) o[dd] *= al;
    }

    // P = exp(S - m), pack to bf16 pairs, row-sum
    unsigned int pk[8];
    float ps = 0.0f;
#pragma unroll
    for (int t = 0; t < 4; ++t) {
      float p0 = exp2f((s[t][0] - m_) * LOG2E);
      float p1 = exp2f((s[t][1] - m_) * LOG2E);
      float p2 = exp2f((s[t][2] - m_) * LOG2E);
      float p3 = exp2f((s[t][3] - m_) * LOG2E);
      ps += (p0 + p1) + (p2 + p3);
      pk[2 * t] = (unsigned int)f2bf(p0) | ((unsigned int)f2bf(p1) << 16);
      pk[2 * t + 1] = (unsigned int)f2bf(p2) | ((unsigned int)f2bf(p3) << 16);
    }
    ps += __shfl_xor(ps, 16);
    ps += __shfl_xor(ps, 32);
    lsum += ps;

    // permute P into B-fragment layout: lane needs P[q=l16][kv=32c+lg*8+j]
    const int srcA = l16 + ((lg & 1) << 5);
    const int srcB = srcA + 16;
    const int hi = lg >> 1;
#pragma unroll
    for (int c = 0; c < 2; ++c) {
      unsigned int d0a = (unsigned int)__shfl((int)pk[4 * c], srcA);
      unsigned int d0b = (unsigned int)__shfl((int)pk[4 * c + 2], srcA);
      unsigned int d1a = (unsigned int)__shfl((int)pk[4 * c + 1], srcA);
      unsigned int d1b = (unsigned int)__shfl((int)pk[4 * c + 3], srcA);
      unsigned int d2a = (unsigned int)__shfl((int)pk[4 * c], srcB);
      unsigned int d2b = (unsigned int)__shfl((int)pk[4 * c + 2], srcB);
      unsigned int d3a = (unsigned int)__shfl((int)pk[4 * c + 1], srcB);
      unsigned int d3b = (unsigned int)__shfl((int)pk[4 * c + 3], srcB);
      u32x4 pw;
      pw[0] = hi ? d0b : d0a;
      pw[1] = hi ? d1b : d1a;
      pw[2] = hi ? d2b : d2a;
      pw[3] = hi ? d3b : d3a;
      bf16x8 pf = __builtin_bit_cast(bf16x8, pw);
#pragma unroll
      for (int dd = 0; dd < 4; ++dd)
        o[dd] = __builtin_amdgcn_mfma_f32_16x16x32_bf16(vf[2 * dd + c], pf, o[dd], 0, 0, 0);
    }

#pragma unroll
    for (int j = 0; j < 8; ++j) kf[j] = kn[j];
  }

  // epilogue: O^T in regs -> out[b][q][d], q = q0+l16, d = 16dd + lg*4 + r
  const float inv = 1.0f / lsum;
  float* op = out + ((size_t)b * SEQ + q0 + l16) * HEAD;
#pragma unroll
  for (int dd = 0; dd < 4; ++dd)
#pragma unroll
    for (int r = 0; r < 4; ++r)
      op[16 * dd + lg * 4 + r] = o[dd][r] * inv;
}

extern "C" void kernel_launch(void* const* d_in, const int* in_sizes, int n_in,
                              void* d_out, int out_size, void* d_ws, size_t ws_size,
                              hipStream_t stream) {
  (void)in_sizes; (void)n_in; (void)out_size; (void)ws_size;
  const float* x = (const float*)d_in[0];
  const float* W = (const float*)d_in[1];
  float* out = (float*)d_out;

  unsigned short* Wt = (unsigned short*)d_ws;                                   // 384 KB
  unsigned short* kq = (unsigned short*)((char*)d_ws + 512 * 1024);             // 8 MB
  unsigned short* Vt = (unsigned short*)((char*)d_ws + 512 * 1024 + (size_t)BATCH * SEQ * KQ_STR * 2);  // 4 MB

  hipLaunchKernelGGL(wt_kernel, dim3((EMB * N3) / 256), dim3(256), 0, stream, W, Wt);
  hipLaunchKernelGGL(qkv_kernel, dim3((BATCH * SEQ) / 32), dim3(512), 0, stream, x, Wt, kq, Vt);
  hipLaunchKernelGGL(attn_kernel, dim3(2 * BATCH * 32), dim3(256), 0, stream, kq, Vt, out);
}

// Round 6
// 154.302 us; speedup vs baseline: 1.7601x; 1.7601x over previous
//
#include <hip/hip_runtime.h>
#include <hip/hip_bf16.h>

#define BATCH 8
#define SEQ 4096
#define EMB 1024
#define HEAD 64
#define N3 192      // 3*HEAD: k | q | v
#define KQ_STR 128  // dense K|Q row stride

#define BM 64       // qkv block rows
#define BK 64       // qkv K-step
#define NT (EMB / BK)
#define LSTR 72     // padded LDS row stride in ushorts (64 + 8): 144B = 9*16B

typedef __attribute__((ext_vector_type(4))) float f32x4;
typedef __attribute__((ext_vector_type(8))) short bf16x8;
typedef __attribute__((ext_vector_type(4))) short short4v;
typedef __attribute__((ext_vector_type(4))) float float4v;
typedef __attribute__((ext_vector_type(4))) unsigned int u32x4;

#define LOG2E 1.4426950408889634f

static __device__ __forceinline__ unsigned short f2bf(float f) {
  unsigned int x = __builtin_bit_cast(unsigned int, f);
  x += 0x7fffu + ((x >> 16) & 1u);   // RTNE
  return (unsigned short)(x >> 16);
}

// --- Kernel 1: W [1024][192] f32 -> Wt [192][1024] bf16 ---
__global__ __launch_bounds__(256) void wt_kernel(const float* __restrict__ W,
                                                 unsigned short* __restrict__ Wt) {
  int idx = blockIdx.x * 256 + threadIdx.x;
  int k = idx / N3, c = idx % N3;
  Wt[(size_t)c * EMB + k] = f2bf(W[idx]);
}

// --- Kernel 2: canonical LDS-staged GEMM. 512 blocks x 256 thr (4 waves).
// Block: 64 rows x 192 cols. Wave w: cols [w*48, w*48+48) = 3 n-frags; 4 m-frags.
// A (x tile) reg-staged fp32->bf16 coalesced; B (Wt tile) reg-staged bf16 coalesced.
// LDS padded stride 144B -> fragment ds_read_b128 is 2-way bank alias (free).
__global__ __launch_bounds__(256, 2) void qkv_kernel(const float* __restrict__ x,
                                                     const unsigned short* __restrict__ Wt,
                                                     unsigned short* __restrict__ kq,
                                                     unsigned short* __restrict__ Vt) {
  __shared__ unsigned short Asm[2][BM][LSTR];    // 2 x 64 x 144B = 18.4 KB
  __shared__ unsigned short Bsm[2][N3][LSTR];    // 2 x 192 x 144B = 55.3 KB

  const int tid = threadIdx.x;
  const int wid = tid >> 6;
  const int lane = tid & 63;
  const int l16 = lane & 15;
  const int lg = lane >> 4;
  const int m0 = blockIdx.x * BM;

  // staging coords (constant per thread)
  const int ar0 = tid >> 4;        // A row base: +16*i, i<4
  const int ac4 = tid & 15;        // A float4-chunk in row (16B, 4 floats)
  const int br0 = tid >> 3;        // B row base: +32*i, i<6
  const int bc = tid & 7;          // B bf16x8-chunk in row (16B)

  const float* xa = x + (size_t)(m0 + ar0) * EMB + ac4 * 4;
  const unsigned short* wb = Wt + (size_t)br0 * EMB + bc * 8;

  f32x4 acc[4][3];
#pragma unroll
  for (int mi = 0; mi < 4; ++mi)
#pragma unroll
    for (int ni = 0; ni < 3; ++ni) acc[mi][ni] = (f32x4)0.0f;

  float4v av[4];
  bf16x8 bv[6];

#define ISSUE_LOADS(K0)                                                        \
  {                                                                            \
    _Pragma("unroll") for (int i = 0; i < 4; ++i)                              \
        av[i] = *(const float4v*)(xa + (size_t)(16 * i) * EMB + (K0));         \
    _Pragma("unroll") for (int i = 0; i < 6; ++i)                              \
        bv[i] = *(const bf16x8*)(wb + (size_t)(32 * i) * EMB + (K0));          \
  }

#define WRITE_LDS(BUF)                                                         \
  {                                                                            \
    _Pragma("unroll") for (int i = 0; i < 4; ++i) {                            \
      short4v p;                                                               \
      _Pragma("unroll") for (int j = 0; j < 4; ++j)                            \
          p[j] = (short)f2bf(av[i][j]);                                        \
      *(short4v*)&Asm[BUF][ar0 + 16 * i][ac4 * 4] = p;                         \
    }                                                                          \
    _Pragma("unroll") for (int i = 0; i < 6; ++i)                              \
        *(bf16x8*)&Bsm[BUF][br0 + 32 * i][bc * 8] = bv[i];                     \
  }

#define COMPUTE(BUF)                                                           \
  {                                                                            \
    _Pragma("unroll") for (int kh = 0; kh < 2; ++kh) {                         \
      bf16x8 af[4], bfr[3];                                                    \
      _Pragma("unroll") for (int mi = 0; mi < 4; ++mi)                         \
          af[mi] = *(const bf16x8*)&Asm[BUF][mi * 16 + l16][kh * 32 + lg * 8]; \
      _Pragma("unroll") for (int ni = 0; ni < 3; ++ni)                         \
          bfr[ni] = *(const bf16x8*)&Bsm[BUF][wid * 48 + ni * 16 + l16][kh * 32 + lg * 8]; \
      _Pragma("unroll") for (int mi = 0; mi < 4; ++mi)                         \
        _Pragma("unroll") for (int ni = 0; ni < 3; ++ni)                       \
            acc[mi][ni] = __builtin_amdgcn_mfma_f32_16x16x32_bf16(             \
                af[mi], bfr[ni], acc[mi][ni], 0, 0, 0);                        \
    }                                                                          \
  }

  // prologue: stage tile 0
  ISSUE_LOADS(0)
  WRITE_LDS(0)
  __syncthreads();

  int cur = 0;
  for (int t = 0; t < NT; ++t) {
    if (t < NT - 1) ISSUE_LOADS((t + 1) * BK)   // early issue: latency hides under MFMA
    COMPUTE(cur)
    if (t < NT - 1) {
      WRITE_LDS(cur ^ 1)
    }
    __syncthreads();
    cur ^= 1;
  }
#undef ISSUE_LOADS
#undef WRITE_LDS
#undef COMPUTE

  // epilogue: D col = n (l16-resident), row = m0 + mi*16 + lg*4 + r
#pragma unroll
  for (int mi = 0; mi < 4; ++mi) {
#pragma unroll
    for (int ni = 0; ni < 3; ++ni) {
      const int n = wid * 48 + ni * 16 + l16;
#pragma unroll
      for (int r = 0; r < 4; ++r) {
        int row = m0 + mi * 16 + lg * 4 + r;
        float v = acc[mi][ni][r];
        if (n >= 64 && n < 128) v *= 0.125f;   // q pre-scale 1/sqrt(64)
        unsigned short h = f2bf(v);
        if (n < 128) {
          kq[(size_t)row * KQ_STR + n] = h;
        } else {
          int bb = row >> 12;
          int ss = row & (SEQ - 1);
          Vt[((size_t)bb * HEAD + (n - 128)) * SEQ + ss] = h;
        }
      }
    }
  }
}

// --- Kernel 3: causal flash attention, barrier-free, one 16-row q-chunk per wave ---
__global__ __launch_bounds__(256) void attn_kernel(const unsigned short* __restrict__ kq,
                                                   const unsigned short* __restrict__ Vt,
                                                   float* __restrict__ out) {
  const int tid = threadIdx.x;
  const int wid = tid >> 6;
  const int lane = tid & 63;
  const int l16 = lane & 15;
  const int lg = lane >> 4;

  // block B and B+256 carry complementary chunk lengths; batch = blockIdx%8 (XCD affinity)
  const int Bid = blockIdx.x;
  const int half = Bid >> 8;
  const int rr = Bid & 255;
  const int b = rr & 7;
  const int ii = rr >> 3;          // [0,32)
  int qc = 4 * ii + wid;           // [0,128)
  if (half) qc = 255 - qc;         // [128,256)
  const int q0 = qc * 16;
  const int ntiles = (q0 + 16 + 63) >> 6;

  const unsigned short* kqb = kq + (size_t)b * SEQ * KQ_STR;
  const unsigned short* vtb = Vt + (size_t)b * HEAD * SEQ;

  // Q fragments (B-operand of S^T mfma): col=l16 -> q row, k=lg*8+j -> d
  bf16x8 qf0 = *(const bf16x8*)(kqb + (size_t)(q0 + l16) * KQ_STR + 64 + lg * 8);
  bf16x8 qf1 = *(const bf16x8*)(kqb + (size_t)(q0 + l16) * KQ_STR + 96 + lg * 8);

  f32x4 o[4];
#pragma unroll
  for (int dd = 0; dd < 4; ++dd) o[dd] = (f32x4)0.0f;
  float m_ = -3.0e38f, lsum = 0.0f;

  // preload K tile 0 (A-operand: row=l16 -> kv, k=lg*8+j -> d)
  bf16x8 kf[8], kn[8];
#pragma unroll
  for (int t = 0; t < 4; ++t) {
    const unsigned short* kp = kqb + (size_t)(t * 16 + l16) * KQ_STR + lg * 8;
    kf[2 * t] = *(const bf16x8*)(kp);
    kf[2 * t + 1] = *(const bf16x8*)(kp + 32);
  }

  for (int it = 0; it < ntiles; ++it) {
    const int kv0 = it << 6;

    // prefetch next K tile (clamped; covered by this tile's compute)
    int kvn = kv0 + 64;
    if (kvn > SEQ - 64) kvn = SEQ - 64;
#pragma unroll
    for (int t = 0; t < 4; ++t) {
      const unsigned short* kp = kqb + (size_t)(kvn + t * 16 + l16) * KQ_STR + lg * 8;
      kn[2 * t] = *(const bf16x8*)(kp);
      kn[2 * t + 1] = *(const bf16x8*)(kp + 32);
    }
    // V fragments for this tile (A-operand of PV: row=l16 -> d, k -> kv)
    bf16x8 vf[8];
#pragma unroll
    for (int dd = 0; dd < 4; ++dd) {
      const unsigned short* vp = vtb + (size_t)(dd * 16 + l16) * SEQ + kv0 + lg * 8;
      vf[2 * dd] = *(const bf16x8*)(vp);
      vf[2 * dd + 1] = *(const bf16x8*)(vp + 32);
    }

    // S^T[kv][q]: lane holds kv = kv0+16t+lg*4+r for q = q0+l16
    f32x4 s[4];
#pragma unroll
    for (int t = 0; t < 4; ++t) {
      f32x4 z = (f32x4)0.0f;
      z = __builtin_amdgcn_mfma_f32_16x16x32_bf16(kf[2 * t], qf0, z, 0, 0, 0);
      z = __builtin_amdgcn_mfma_f32_16x16x32_bf16(kf[2 * t + 1], qf1, z, 0, 0, 0);
      s[t] = z;
    }

    // causal mask only on diagonal-crossing tiles (uniform branch)
    if (kv0 + 64 > q0) {
      const int base = kv0 + lg * 4 - q0 - l16;   // masked iff base + 16t + r > 0
#pragma unroll
      for (int t = 0; t < 4; ++t)
#pragma unroll
        for (int r = 0; r < 4; ++r)
          if (base + 16 * t + r > 0) s[t][r] = -3.0e38f;
    }

    // row max: 15 in-lane fmax + 2 shfl (across lg groups)
    float mx = s[0][0];
#pragma unroll
    for (int t = 0; t < 4; ++t)
#pragma unroll
      for (int r = 0; r < 4; ++r)
        mx = fmaxf(mx, s[t][r]);
    mx = fmaxf(mx, __shfl_xor(mx, 16));
    mx = fmaxf(mx, __shfl_xor(mx, 32));

    // defer-max: rescale only when some row's max grew
    if (!__all(mx <= m_)) {
      float mn = fmaxf(m_, mx);
      float al = exp2f((m_ - mn) * LOG2E);
      m_ = mn;
      lsum *= al;
#pragma unroll
      for (int dd = 0; dd < 4; ++dd) o[dd] *= al;
    }

    // P = exp(S - m), pack to bf16 pairs, row-sum
    unsigned int pk[8];
    float ps = 0.0f;
#pragma unroll
    for (int t = 0; t < 4; ++t) {
      float p0 = exp2f((s[t][0] - m_) * LOG2E);
      float p1 = exp2f((s[t][1] - m_) * LOG2E);
      float p2 = exp2f((s[t][2] - m_) * LOG2E);
      float p3 = exp2f((s[t][3] - m_) * LOG2E);
      ps += (p0 + p1) + (p2 + p3);
      pk[2 * t] = (unsigned int)f2bf(p0) | ((unsigned int)f2bf(p1) << 16);
      pk[2 * t + 1] = (unsigned int)f2bf(p2) | ((unsigned int)f2bf(p3) << 16);
    }
    ps += __shfl_xor(ps, 16);
    ps += __shfl_xor(ps, 32);
    lsum += ps;

    // permute P into B-fragment layout: lane needs P[q=l16][kv=32c+lg*8+j]
    const int srcA = l16 + ((lg & 1) << 5);
    const int srcB = srcA + 16;
    const int hi = lg >> 1;
#pragma unroll
    for (int c = 0; c < 2; ++c) {
      unsigned int d0a = (unsigned int)__shfl((int)pk[4 * c], srcA);
      unsigned int d0b = (unsigned int)__shfl((int)pk[4 * c + 2], srcA);
      unsigned int d1a = (unsigned int)__shfl((int)pk[4 * c + 1], srcA);
      unsigned int d1b = (unsigned int)__shfl((int)pk[4 * c + 3], srcA);
      unsigned int d2a = (unsigned int)__shfl((int)pk[4 * c], srcB);
      unsigned int d2b = (unsigned int)__shfl((int)pk[4 * c + 2], srcB);
      unsigned int d3a = (unsigned int)__shfl((int)pk[4 * c + 1], srcB);
      unsigned int d3b = (unsigned int)__shfl((int)pk[4 * c + 3], srcB);
      u32x4 pw;
      pw[0] = hi ? d0b : d0a;
      pw[1] = hi ? d1b : d1a;
      pw[2] = hi ? d2b : d2a;
      pw[3] = hi ? d3b : d3a;
      bf16x8 pf = __builtin_bit_cast(bf16x8, pw);
#pragma unroll
      for (int dd = 0; dd < 4; ++dd)
        o[dd] = __builtin_amdgcn_mfma_f32_16x16x32_bf16(vf[2 * dd + c], pf, o[dd], 0, 0, 0);
    }

#pragma unroll
    for (int j = 0; j < 8; ++j) kf[j] = kn[j];
  }

  // epilogue: O^T in regs -> out[b][q][d], q = q0+l16, d = 16dd + lg*4 + r
  const float inv = 1.0f / lsum;
  float* op = out + ((size_t)b * SEQ + q0 + l16) * HEAD;
#pragma unroll
  for (int dd = 0; dd < 4; ++dd)
#pragma unroll
    for (int r = 0; r < 4; ++r)
      op[16 * dd + lg * 4 + r] = o[dd][r] * inv;
}

extern "C" void kernel_launch(void* const* d_in, const int* in_sizes, int n_in,
                              void* d_out, int out_size, void* d_ws, size_t ws_size,
                              hipStream_t stream) {
  (void)in_sizes; (void)n_in; (void)out_size; (void)ws_size;
  const float* x = (const float*)d_in[0];
  const float* W = (const float*)d_in[1];
  float* out = (float*)d_out;

  unsigned short* Wt = (unsigned short*)d_ws;                                   // 384 KB
  unsigned short* kq = (unsigned short*)((char*)d_ws + 512 * 1024);             // 8 MB
  unsigned short* Vt = (unsigned short*)((char*)d_ws + 512 * 1024 + (size_t)BATCH * SEQ * KQ_STR * 2);  // 4 MB

  hipLaunchKernelGGL(wt_kernel, dim3((EMB * N3) / 256), dim3(256), 0, stream, W, Wt);
  hipLaunchKernelGGL(qkv_kernel, dim3((BATCH * SEQ) / BM), dim3(256), 0, stream, x, Wt, kq, Vt);
  hipLaunchKernelGGL(attn_kernel, dim3(2 * BATCH * 32), dim3(256), 0, stream, kq, Vt, out);
}